// Round 14
// baseline (1808.854 us; speedup 1.0000x reference)
//
#include <hip/hip_runtime.h>
#include <stdint.h>

#define NPTS 16384
#define BATCH 16
#define FPS_N 512
#define NANCH 50
#define TOPK 4
#define NBH 128
#define BALLK 1000

#define FT 256        // 4 waves/block, 1 wave/SIMD -> 512-VGPR cap, narrow barrier
#define NW 4

#define CTRL_XOR1 0xB1
#define CTRL_XOR2 0x4E
#define CTRL_ROR4 0x124
#define CTRL_ROR8 0x128

#define DPP_MAX64(v, CTRL) do {                                                   \
  unsigned int _lo = (unsigned int)(v);                                           \
  unsigned int _hi = (unsigned int)((v) >> 32);                                   \
  unsigned int _slo = (unsigned int)__builtin_amdgcn_update_dpp((int)_lo, (int)_lo, CTRL, 0xf, 0xf, false); \
  unsigned int _shi = (unsigned int)__builtin_amdgcn_update_dpp((int)_hi, (int)_hi, CTRL, 0xf, 0xf, false); \
  unsigned long long _o = (((unsigned long long)_shi) << 32) | _slo;              \
  if (_o > (v)) (v) = _o;                                                         \
} while (0)

#define DPP_MIN64(v, CTRL) do {                                                   \
  unsigned int _lo = (unsigned int)(v);                                           \
  unsigned int _hi = (unsigned int)((v) >> 32);                                   \
  unsigned int _slo = (unsigned int)__builtin_amdgcn_update_dpp((int)_lo, (int)_lo, CTRL, 0xf, 0xf, false); \
  unsigned int _shi = (unsigned int)__builtin_amdgcn_update_dpp((int)_hi, (int)_hi, CTRL, 0xf, 0xf, false); \
  unsigned long long _o = (((unsigned long long)_shi) << 32) | _slo;              \
  if (_o < (v)) (v) = _o;                                                         \
} while (0)

#define SWZ16_MIN64(v) do {                                                       \
  unsigned int _lo = (unsigned int)(v), _hi = (unsigned int)((v) >> 32);          \
  unsigned int _slo = (unsigned int)__builtin_amdgcn_ds_swizzle((int)_lo, 0x401f);\
  unsigned int _shi = (unsigned int)__builtin_amdgcn_ds_swizzle((int)_hi, 0x401f);\
  unsigned long long _o = (((unsigned long long)_shi) << 32) | _slo;              \
  if (_o < (v)) (v) = _o;                                                         \
} while (0)

#define SHF32_MIN64(v) do {                                                       \
  unsigned long long _o = __shfl_xor((v), 32, 64);                                \
  if (_o < (v)) (v) = _o;                                                         \
} while (0)

__device__ __forceinline__ uint32_t f2key(float f) {
  uint32_t u = __float_as_uint(f);
  return (u & 0x80000000u) ? ~u : (u | 0x80000000u);
}

#define REP32(OP) OP(0) OP(1) OP(2) OP(3) OP(4) OP(5) OP(6) OP(7) \
  OP(8) OP(9) OP(10) OP(11) OP(12) OP(13) OP(14) OP(15) \
  OP(16) OP(17) OP(18) OP(19) OP(20) OP(21) OP(22) OP(23) \
  OP(24) OP(25) OP(26) OP(27) OP(28) OP(29) OP(30) OP(31)

// 48 blocks x 256 threads. Blocks 0..15: full 512-step FPS. Blocks 16..47:
// workers (b=(bid-16)>>1, pair p): 50-step seed (bit-identical), counts, top4,
// 2x 128-NN, roi. 64 pts/thread in NAMED registers (512-VGPR cap at 1 wave/EU:
// no spill, no remat); tail issues once/SIMD; 4-wave barrier; 2-step cross-wave.
__global__ __launch_bounds__(FT, 1) void mega_kernel(const float* __restrict__ pts,
                                                     float* __restrict__ out) {
  __shared__ unsigned long long s_key[2][NW];
  __shared__ float4 s_xyz[2][NW];
  __shared__ float4 s_anch[NANCH];
  __shared__ int s_cnt[NANCH];
  __shared__ int s_t4[TOPK];
  __shared__ int s_knn[NBH];

  const int bid = blockIdx.x;
  const bool isFps = bid < BATCH;
  const int b = isFps ? bid : ((bid - BATCH) >> 1);
  const int p = (bid - BATCH) & 1;
  const int nsteps = isFps ? FPS_N : NANCH;

  const int t = threadIdx.x;
  const int lane = t & 63;
  const int wS = t >> 6;                    // wave 0..3
  const float* __restrict__ px = pts + (size_t)b * 3 * NPTS;
  const float* __restrict__ py = px + NPTS;
  const float* __restrict__ pz = py + NPTS;

#define DECLK(k) float2 x_##k, y_##k, z_##k, d_##k;
  REP32(DECLK)
#undef DECLK
#define LOADK(k) { const int i2 = ((k) << 9) + (t << 1);                   \
    x_##k = *(const float2*)&px[i2];                                       \
    y_##k = *(const float2*)&py[i2];                                       \
    z_##k = *(const float2*)&pz[i2];                                       \
    d_##k = make_float2(1e10f, 1e10f); }
  REP32(LOADK)
#undef LOADK
#define PINK(k) asm volatile("" : "+v"(x_##k), "+v"(y_##k), "+v"(z_##k));
  REP32(PINK)
#undef PINK

  float bx = px[0], by = py[0], bz = pz[0];
  if (t == 0) {
    if (isFps) {
      float* o = out + ((size_t)b * 1536 + 1024) * 3;
      o[0] = bx; o[1] = by; o[2] = bz;
    } else {
      s_anch[0] = make_float4(bx, by, bz, 0.f);
    }
  }

  // ---- FPS loop (identical for fps & worker seed -> bit-identical picks) ----
  for (int step = 1; step < nsteps; ++step) {
    const int par = step & 1;
    const float2 nbx2 = make_float2(-bx, -bx);
    const float2 nby2 = make_float2(-by, -by);
    const float2 nbz2 = make_float2(-bz, -bz);
    float run = -1.0f;
    // exact: d = ((x-bx)^2 + (y-by)^2) + (z-bz)^2, rn (x + (-bx) == x - bx)
#define FPSK(k) {                                                          \
    float2 t0, t1, t2;                                                     \
    asm("v_pk_add_f32 %0, %3, %6\n\t"                                      \
        "v_pk_add_f32 %1, %4, %7\n\t"                                      \
        "v_pk_add_f32 %2, %5, %8\n\t"                                      \
        "v_pk_mul_f32 %0, %0, %0\n\t"                                      \
        "v_pk_mul_f32 %1, %1, %1\n\t"                                      \
        "v_pk_mul_f32 %2, %2, %2\n\t"                                      \
        "v_pk_add_f32 %0, %0, %1\n\t"                                      \
        "v_pk_add_f32 %0, %0, %2"                                          \
        : "=&v"(t0), "=&v"(t1), "=&v"(t2)                                  \
        : "v"(x_##k), "v"(y_##k), "v"(z_##k), "v"(nbx2), "v"(nby2), "v"(nbz2)); \
    d_##k.x = fminf(d_##k.x, t0.x);                                        \
    d_##k.y = fminf(d_##k.y, t0.y);                                        \
    asm("v_max3_f32 %0, %0, %1, %2"                                        \
        : "+v"(run) : "v"(d_##k.x), "v"(d_##k.y)); }
    REP32(FPSK)
#undef FPSK
    // wave max: DPP row-reduce + readlane/s_max (SGPR result)
    uint32_t m = __float_as_uint(run);
    {
      uint32_t s;
      s = (uint32_t)__builtin_amdgcn_update_dpp((int)m, (int)m, CTRL_XOR1, 0xf, 0xf, false); m = m > s ? m : s;
      s = (uint32_t)__builtin_amdgcn_update_dpp((int)m, (int)m, CTRL_XOR2, 0xf, 0xf, false); m = m > s ? m : s;
      s = (uint32_t)__builtin_amdgcn_update_dpp((int)m, (int)m, CTRL_ROR4, 0xf, 0xf, false); m = m > s ? m : s;
      s = (uint32_t)__builtin_amdgcn_update_dpp((int)m, (int)m, CTRL_ROR8, 0xf, 0xf, false); m = m > s ? m : s;
    }
    const uint32_t r0 = (uint32_t)__builtin_amdgcn_readlane((int)m, 0);
    const uint32_t r1 = (uint32_t)__builtin_amdgcn_readlane((int)m, 16);
    const uint32_t r2 = (uint32_t)__builtin_amdgcn_readlane((int)m, 32);
    const uint32_t r3 = (uint32_t)__builtin_amdgcn_readlane((int)m, 48);
    const uint32_t ra = r0 > r1 ? r0 : r1;
    const uint32_t rb = r2 > r3 ? r2 : r3;
    const uint32_t wm = ra > rb ? ra : rb;
    const float gmaxf = __uint_as_float(wm);
    // lowest idx achieving wave max; winner lane stages xyz (static k)
    uint32_t widx_w = 0u;
    bool done = false;
#define BALK(k) {                                                          \
    const unsigned long long b0 = __ballot(d_##k.x == gmaxf);              \
    const unsigned long long b1 = __ballot(d_##k.y == gmaxf);              \
    const unsigned long long cb = b0 | b1;                                 \
    if (!done && cb) {                                                     \
      const int l = (int)__builtin_ctzll(cb);                              \
      const uint32_t pp = ((b0 >> l) & 1ull) ? 0u : 1u;                    \
      widx_w = ((uint32_t)(k) << 9) + ((uint32_t)((wS << 6) | l) << 1) + pp; \
      if (lane == l) {                                                     \
        const float cx = pp ? x_##k.y : x_##k.x;                           \
        const float cy = pp ? y_##k.y : y_##k.x;                           \
        const float cz = pp ? z_##k.y : z_##k.x;                           \
        s_xyz[par][wS] = make_float4(cx, cy, cz, 0.f);                     \
      }                                                                    \
      done = true;                                                         \
    } }
    REP32(BALK)
#undef BALK
    if (lane == 0)
      s_key[par][wS] = ((unsigned long long)wm << 32) | (uint32_t)(~widx_w);
    __syncthreads();
    // cross-wave: 4 partials -> 2 DPP quad steps; overlapped key+xyz reads
    unsigned long long g = s_key[par][lane & 3];
    const float4 cand = s_xyz[par][lane & 3];
    DPP_MAX64(g, CTRL_XOR1);
    DPP_MAX64(g, CTRL_XOR2);
    const uint32_t widx = ~(uint32_t)g;
    const int wstar = (int)((widx >> 7) & 3);     // owning wave of winner
    const int sw = __builtin_amdgcn_readfirstlane(wstar);
    bx = __uint_as_float((uint32_t)__builtin_amdgcn_readlane((int)__float_as_uint(cand.x), sw));
    by = __uint_as_float((uint32_t)__builtin_amdgcn_readlane((int)__float_as_uint(cand.y), sw));
    bz = __uint_as_float((uint32_t)__builtin_amdgcn_readlane((int)__float_as_uint(cand.z), sw));
    if (t == 0) {
      if (isFps) {
        float* o = out + ((size_t)b * 1536 + 1024 + step) * 3;
        o[0] = bx; o[1] = by; o[2] = bz;
      } else {
        s_anch[step] = make_float4(bx, by, bz, 0.f);
      }
    }
  }
  if (isFps) return;

  // ================= worker path (b, anchor pair p) =================
#define DECLP(k) float2 p_##k;
  REP32(DECLP)
#undef DECLP
#define PSUMK(k) {                                                         \
    float2 s0, s1, s2;                                                     \
    asm("v_pk_mul_f32 %0, %3, %3\n\t"                                      \
        "v_pk_mul_f32 %1, %4, %4\n\t"                                      \
        "v_pk_mul_f32 %2, %5, %5\n\t"                                      \
        "v_pk_add_f32 %0, %0, %1\n\t"                                      \
        "v_pk_add_f32 %0, %0, %2"                                          \
        : "=&v"(s0), "=&v"(s1), "=&v"(s2)                                  \
        : "v"(x_##k), "v"(y_##k), "v"(z_##k));                             \
    p_##k = s0; }
  REP32(PSUMK)
#undef PSUMK
  if (t < NANCH) s_cnt[t] = 0;
  __syncthreads();

  const float R2 = (float)(0.4 * 0.4);
  const float2 mm2 = make_float2(-2.0f, -2.0f);
  for (int a = 0; a < NANCH; ++a) {
    const float4 A = s_anch[a];
    const float ax = A.x, ay = A.y, az = A.z;
    const float asum = __fadd_rn(__fadd_rn(__fmul_rn(ax, ax), __fmul_rn(ay, ay)),
                                 __fmul_rn(az, az));
    const float2 ax2 = make_float2(ax, ax);
    const float2 ay2 = make_float2(ay, ay);
    const float2 az2 = make_float2(az, az);
    const float2 as2 = make_float2(asum, asum);
    int cw = 0;
#define CNTK(k) {                                                          \
    float2 d0, d1, d2v;                                                    \
    asm("v_pk_mul_f32 %0, %3, %6\n\t"                                      \
        "v_pk_mul_f32 %1, %4, %7\n\t"                                      \
        "v_pk_mul_f32 %2, %5, %8\n\t"                                      \
        "v_pk_add_f32 %0, %0, %1\n\t"                                      \
        "v_pk_add_f32 %0, %0, %2\n\t"                                      \
        "v_pk_mul_f32 %0, %0, %9\n\t"                                      \
        "v_pk_add_f32 %0, %0, %10\n\t"                                     \
        "v_pk_add_f32 %0, %0, %11"                                         \
        : "=&v"(d0), "=&v"(d1), "=&v"(d2v)                                 \
        : "v"(x_##k), "v"(y_##k), "v"(z_##k), "v"(ax2), "v"(ay2), "v"(az2),\
          "v"(mm2), "v"(as2), "v"(p_##k));                                 \
    cw += (int)__popcll(__ballot(d0.x < R2));                              \
    cw += (int)__popcll(__ballot(d0.y < R2)); }
    REP32(CNTK)
#undef CNTK
    if (lane == 0) atomicAdd(&s_cnt[a], cw);
  }
  __syncthreads();

  if (t == 0) {
    unsigned long long used = 0ULL;
    for (int r = 0; r < TOPK; ++r) {
      int bestc = -1, besta = 0;
      for (int a = 0; a < NANCH; ++a) {
        if (used & (1ULL << a)) continue;
        int c = s_cnt[a];
        c = c < BALLK ? c : BALLK;
        if (c > bestc) { bestc = c; besta = a; }   // strict > : lowest slot on ties
      }
      used |= 1ULL << besta;
      s_t4[r] = besta;
    }
  }
  __syncthreads();

  // ---- two 128-NN searches: anchors j = 2p, 2p+1 ----
  for (int jj = 0; jj < 2; ++jj) {
    const int j = 2 * p + jj;
    const float4 A = s_anch[s_t4[j]];
    const float ax = A.x, ay = A.y, az = A.z;
    const float asum = __fadd_rn(__fadd_rn(__fmul_rn(ax, ax), __fmul_rn(ay, ay)),
                                 __fmul_rn(az, az));
    const float2 ax2 = make_float2(ax, ax);
    const float2 ay2 = make_float2(ay, ay);
    const float2 az2 = make_float2(az, az);
    const float2 as2 = make_float2(asum, asum);
#define DECLKK(k) unsigned long long ka_##k, kb_##k;
    REP32(DECLKK)
#undef DECLKK
#define KEYK(k) {                                                          \
    float2 d0, d1, d2v;                                                    \
    asm("v_pk_mul_f32 %0, %3, %6\n\t"                                      \
        "v_pk_mul_f32 %1, %4, %7\n\t"                                      \
        "v_pk_mul_f32 %2, %5, %8\n\t"                                      \
        "v_pk_add_f32 %0, %0, %1\n\t"                                      \
        "v_pk_add_f32 %0, %0, %2\n\t"                                      \
        "v_pk_mul_f32 %0, %0, %9\n\t"                                      \
        "v_pk_add_f32 %0, %0, %10\n\t"                                     \
        "v_pk_add_f32 %0, %0, %11"                                         \
        : "=&v"(d0), "=&v"(d1), "=&v"(d2v)                                 \
        : "v"(x_##k), "v"(y_##k), "v"(z_##k), "v"(ax2), "v"(ay2), "v"(az2),\
          "v"(mm2), "v"(as2), "v"(p_##k));                                 \
    const int i2 = ((k) << 9) + (t << 1);                                  \
    ka_##k = ((unsigned long long)f2key(d0.x) << 32) | (uint32_t)i2;       \
    kb_##k = ((unsigned long long)f2key(d0.y) << 32) | (uint32_t)(i2 + 1); }
    REP32(KEYK)
#undef KEYK
    for (int r = 0; r < NBH; ++r) {
#define PMINK(k) const unsigned long long w_##k = ka_##k < kb_##k ? ka_##k : kb_##k;
      REP32(PMINK)
#undef PMINK
#define U16(k) const unsigned long long u_##k = w_##k < w_##k##_PLUS ? w_##k : w_##k##_PLUS;
      // 32 -> 16 -> 8 -> 4 -> 2 -> 1 tree (explicit)
      const unsigned long long u0 = w_0 < w_16 ? w_0 : w_16;
      const unsigned long long u1 = w_1 < w_17 ? w_1 : w_17;
      const unsigned long long u2 = w_2 < w_18 ? w_2 : w_18;
      const unsigned long long u3 = w_3 < w_19 ? w_3 : w_19;
      const unsigned long long u4 = w_4 < w_20 ? w_4 : w_20;
      const unsigned long long u5 = w_5 < w_21 ? w_5 : w_21;
      const unsigned long long u6 = w_6 < w_22 ? w_6 : w_22;
      const unsigned long long u7 = w_7 < w_23 ? w_7 : w_23;
      const unsigned long long u8 = w_8 < w_24 ? w_8 : w_24;
      const unsigned long long u9 = w_9 < w_25 ? w_9 : w_25;
      const unsigned long long u10 = w_10 < w_26 ? w_10 : w_26;
      const unsigned long long u11 = w_11 < w_27 ? w_11 : w_27;
      const unsigned long long u12 = w_12 < w_28 ? w_12 : w_28;
      const unsigned long long u13 = w_13 < w_29 ? w_13 : w_29;
      const unsigned long long u14 = w_14 < w_30 ? w_14 : w_30;
      const unsigned long long u15 = w_15 < w_31 ? w_15 : w_31;
      const unsigned long long v0 = u0 < u8 ? u0 : u8;
      const unsigned long long v1 = u1 < u9 ? u1 : u9;
      const unsigned long long v2 = u2 < u10 ? u2 : u10;
      const unsigned long long v3 = u3 < u11 ? u3 : u11;
      const unsigned long long v4 = u4 < u12 ? u4 : u12;
      const unsigned long long v5 = u5 < u13 ? u5 : u13;
      const unsigned long long v6 = u6 < u14 ? u6 : u14;
      const unsigned long long v7 = u7 < u15 ? u7 : u15;
      const unsigned long long q0 = v0 < v4 ? v0 : v4;
      const unsigned long long q1 = v1 < v5 ? v1 : v5;
      const unsigned long long q2 = v2 < v6 ? v2 : v6;
      const unsigned long long q3 = v3 < v7 ? v3 : v7;
      const unsigned long long r0m = q0 < q2 ? q0 : q2;
      const unsigned long long r1m = q1 < q3 ? q1 : q3;
      unsigned long long m = r0m < r1m ? r0m : r1m;

      DPP_MIN64(m, CTRL_XOR1);
      DPP_MIN64(m, CTRL_XOR2);
      DPP_MIN64(m, CTRL_ROR4);
      DPP_MIN64(m, CTRL_ROR8);
      SWZ16_MIN64(m);
      SHF32_MIN64(m);

      const int par = r & 1;
      if (lane == 0) s_key[par][wS] = m;
      __syncthreads();
      unsigned long long g = s_key[par][lane & 3];
      DPP_MIN64(g, CTRL_XOR1);
      DPP_MIN64(g, CTRL_XOR2);
      if (t == 0) s_knn[r] = (int)(uint32_t)g;
#define KILLK(k) { if (ka_##k == g) ka_##k = ~0ULL; if (kb_##k == g) kb_##k = ~0ULL; }
      REP32(KILLK)
#undef KILLK
    }
    __syncthreads();
    // write roi1 & roi2 rows for anchor j
    if (t < NBH) {
      const int idx = s_knn[t];
      const float X = px[idx], Y = py[idx], Z = pz[idx];
      float* o1 = out + ((size_t)b * 1536 + (j << 7) + t) * 3;
      float* o2 = o1 + 512 * 3;
      o1[0] = X; o1[1] = Y; o1[2] = Z;
      o2[0] = X; o2[1] = Y; o2[2] = Z;
    }
    __syncthreads();
  }
}

extern "C" void kernel_launch(void* const* d_in, const int* in_sizes, int n_in,
                              void* d_out, int out_size, void* d_ws, size_t ws_size,
                              hipStream_t stream) {
  const float* pts = (const float*)d_in[0];   // [16, 3, 16384]
  float* out = (float*)d_out;                 // [16, 1536, 3]
  (void)d_ws; (void)ws_size;
  mega_kernel<<<dim3(BATCH + 2 * BATCH), dim3(FT), 0, stream>>>(pts, out);
}

// Round 15
// 898.440 us; speedup vs baseline: 2.0133x; 2.0133x over previous
//
#include <hip/hip_runtime.h>
#include <stdint.h>

#define NPTS 16384
#define BATCH 16
#define FPS_N 512
#define NANCH 50
#define TOPK 4
#define NBH 128
#define BALLK 1000

#define FT 1024
#define NW 16

#define CTRL_XOR1 0xB1
#define CTRL_XOR2 0x4E
#define CTRL_ROR4 0x124
#define CTRL_ROR8 0x128

#define DPP_MAX64(v, CTRL) do {                                                   \
  unsigned int _lo = (unsigned int)(v);                                           \
  unsigned int _hi = (unsigned int)((v) >> 32);                                   \
  unsigned int _slo = (unsigned int)__builtin_amdgcn_update_dpp((int)_lo, (int)_lo, CTRL, 0xf, 0xf, false); \
  unsigned int _shi = (unsigned int)__builtin_amdgcn_update_dpp((int)_hi, (int)_hi, CTRL, 0xf, 0xf, false); \
  unsigned long long _o = (((unsigned long long)_shi) << 32) | _slo;              \
  if (_o > (v)) (v) = _o;                                                         \
} while (0)

#define DPP_MIN64(v, CTRL) do {                                                   \
  unsigned int _lo = (unsigned int)(v);                                           \
  unsigned int _hi = (unsigned int)((v) >> 32);                                   \
  unsigned int _slo = (unsigned int)__builtin_amdgcn_update_dpp((int)_lo, (int)_lo, CTRL, 0xf, 0xf, false); \
  unsigned int _shi = (unsigned int)__builtin_amdgcn_update_dpp((int)_hi, (int)_hi, CTRL, 0xf, 0xf, false); \
  unsigned long long _o = (((unsigned long long)_shi) << 32) | _slo;              \
  if (_o < (v)) (v) = _o;                                                         \
} while (0)

#define SWZ16_MIN64(v) do {                                                       \
  unsigned int _lo = (unsigned int)(v), _hi = (unsigned int)((v) >> 32);          \
  unsigned int _slo = (unsigned int)__builtin_amdgcn_ds_swizzle((int)_lo, 0x401f);\
  unsigned int _shi = (unsigned int)__builtin_amdgcn_ds_swizzle((int)_hi, 0x401f);\
  unsigned long long _o = (((unsigned long long)_shi) << 32) | _slo;              \
  if (_o < (v)) (v) = _o;                                                         \
} while (0)

#define SHF32_MIN64(v) do {                                                       \
  unsigned long long _o = __shfl_xor((v), 32, 64);                                \
  if (_o < (v)) (v) = _o;                                                         \
} while (0)

__device__ __forceinline__ uint32_t f2key(float f) {
  uint32_t u = __float_as_uint(f);
  return (u & 0x80000000u) ? ~u : (u | 0x80000000u);
}

#define REP8(OP) OP(0) OP(1) OP(2) OP(3) OP(4) OP(5) OP(6) OP(7)

// r11 structure (best fused family: 932us) with the asm pins REMOVED: at
// 1024 thr the pins forced ~96 state regs over the 128-VGPR cap -> 2.8MB
// scratch spill per dispatch. Remat-from-L2 per step is the proven-fast
// regime (r2-r5 fps-only: 864-880us) and costs no scratch.
__global__ __launch_bounds__(FT, 4) void mega_kernel(const float* __restrict__ pts,
                                                     float* __restrict__ out) {
  __shared__ unsigned long long s_key[2][NW];
  __shared__ float4 s_xyz[2][NW];
  __shared__ float4 s_anch[NANCH];
  __shared__ int s_cnt[NANCH];
  __shared__ int s_t4[TOPK];
  __shared__ int s_knn[NBH];

  const int bid = blockIdx.x;
  const bool isFps = bid < BATCH;
  const int b = isFps ? bid : ((bid - BATCH) >> 1);
  const int p = (bid - BATCH) & 1;          // anchor-pair for workers
  const int nsteps = isFps ? FPS_N : NANCH;

  const int t = threadIdx.x;
  const int lane = t & 63;
  const int wS = t >> 6;                    // wave 0..15
  const float* __restrict__ px = pts + (size_t)b * 3 * NPTS;
  const float* __restrict__ py = px + NPTS;
  const float* __restrict__ pz = py + NPTS;

#define DECLK(k) float2 x_##k, y_##k, z_##k, d_##k;
  REP8(DECLK)
#undef DECLK
#define LOADK(k) { const int i2 = ((k) << 11) + (t << 1);                  \
    x_##k = *(const float2*)&px[i2];                                       \
    y_##k = *(const float2*)&py[i2];                                       \
    z_##k = *(const float2*)&pz[i2];                                       \
    d_##k = make_float2(1e10f, 1e10f); }
  REP8(LOADK)
#undef LOADK
  // NOTE: no pins. Compiler may remat coord loads in-loop from L2; at 16
  // waves/CU those loads hide under the reduce tail (r2-r5 evidence).

  float bx = px[0], by = py[0], bz = pz[0];
  if (t == 0) {
    if (isFps) {
      float* o = out + ((size_t)b * 1536 + 1024) * 3;
      o[0] = bx; o[1] = by; o[2] = bz;
    } else {
      s_anch[0] = make_float4(bx, by, bz, 0.f);
    }
  }

  // ---- FPS loop (identical for fps & worker seed -> bit-identical picks) ----
  for (int step = 1; step < nsteps; ++step) {
    const int par = step & 1;
    const float2 nbx2 = make_float2(-bx, -bx);
    const float2 nby2 = make_float2(-by, -by);
    const float2 nbz2 = make_float2(-bz, -bz);
    float run = -1.0f;
    // exact: d = ((x-bx)^2 + (y-by)^2) + (z-bz)^2, rn (x + (-bx) == x - bx)
#define FPSK(k) {                                                          \
    float2 t0, t1, t2;                                                     \
    asm("v_pk_add_f32 %0, %3, %6\n\t"                                      \
        "v_pk_add_f32 %1, %4, %7\n\t"                                      \
        "v_pk_add_f32 %2, %5, %8\n\t"                                      \
        "v_pk_mul_f32 %0, %0, %0\n\t"                                      \
        "v_pk_mul_f32 %1, %1, %1\n\t"                                      \
        "v_pk_mul_f32 %2, %2, %2\n\t"                                      \
        "v_pk_add_f32 %0, %0, %1\n\t"                                      \
        "v_pk_add_f32 %0, %0, %2"                                          \
        : "=&v"(t0), "=&v"(t1), "=&v"(t2)                                  \
        : "v"(x_##k), "v"(y_##k), "v"(z_##k), "v"(nbx2), "v"(nby2), "v"(nbz2)); \
    d_##k.x = fminf(d_##k.x, t0.x);                                        \
    d_##k.y = fminf(d_##k.y, t0.y);                                        \
    asm("v_max3_f32 %0, %0, %1, %2"                                        \
        : "+v"(run) : "v"(d_##k.x), "v"(d_##k.y)); }
    REP8(FPSK)
#undef FPSK
    // wave max of value (u32 bit-order ok: dist >= 0)
    uint32_t m = __float_as_uint(run);
    {
      uint32_t s;
      s = (uint32_t)__builtin_amdgcn_update_dpp((int)m, (int)m, CTRL_XOR1, 0xf, 0xf, false); m = m > s ? m : s;
      s = (uint32_t)__builtin_amdgcn_update_dpp((int)m, (int)m, CTRL_XOR2, 0xf, 0xf, false); m = m > s ? m : s;
      s = (uint32_t)__builtin_amdgcn_update_dpp((int)m, (int)m, CTRL_ROR4, 0xf, 0xf, false); m = m > s ? m : s;
      s = (uint32_t)__builtin_amdgcn_update_dpp((int)m, (int)m, CTRL_ROR8, 0xf, 0xf, false); m = m > s ? m : s;
      s = (uint32_t)__builtin_amdgcn_ds_swizzle((int)m, 0x401f);                              m = m > s ? m : s;
      s = (uint32_t)__shfl_xor((int)m, 32, 64);                                              m = m > s ? m : s;
    }
    const float gmaxf = __uint_as_float(m);
    // lowest idx achieving the wave max; winner lane stages xyz from registers
    uint32_t widx_w = 0u;
    bool done = false;
#define BALK(k) {                                                          \
    const unsigned long long b0 = __ballot(d_##k.x == gmaxf);              \
    const unsigned long long b1 = __ballot(d_##k.y == gmaxf);              \
    const unsigned long long cb = b0 | b1;                                 \
    if (!done && cb) {                                                     \
      const int l = (int)__builtin_ctzll(cb);                              \
      const uint32_t pp = ((b0 >> l) & 1ull) ? 0u : 1u;                    \
      widx_w = ((uint32_t)(k) << 11) + ((uint32_t)((wS << 6) | l) << 1) + pp; \
      if (lane == l) {                                                     \
        const float cx = pp ? x_##k.y : x_##k.x;                           \
        const float cy = pp ? y_##k.y : y_##k.x;                           \
        const float cz = pp ? z_##k.y : z_##k.x;                           \
        s_xyz[par][wS] = make_float4(cx, cy, cz, 0.f);                     \
      }                                                                    \
      done = true;                                                         \
    } }
    REP8(BALK)
#undef BALK
    if (lane == 0)
      s_key[par][wS] = ((unsigned long long)m << 32) | (uint32_t)(~widx_w);
    __syncthreads();
    // cross-wave max over 16 partials; widx is then wave-uniform
    unsigned long long g = s_key[par][lane & 15];
    DPP_MAX64(g, CTRL_XOR1);
    DPP_MAX64(g, CTRL_XOR2);
    DPP_MAX64(g, CTRL_ROR4);
    DPP_MAX64(g, CTRL_ROR8);
    const uint32_t widx = ~(uint32_t)g;
    const int wstar = (int)((widx >> 7) & 15);   // owning wave of winner
    const float4 W = s_xyz[par][wstar];          // uniform ds_read_b128 (broadcast)
    bx = W.x; by = W.y; bz = W.z;
    if (t == 0) {
      if (isFps) {
        float* o = out + ((size_t)b * 1536 + 1024 + step) * 3;
        o[0] = bx; o[1] = by; o[2] = bz;
      } else {
        s_anch[step] = make_float4(bx, by, bz, 0.f);
      }
    }
  }
  if (isFps) return;

  // ================= worker path (b, anchor pair p) =================
#define DECLP(k) float2 p_##k;
  REP8(DECLP)
#undef DECLP
#define PSUMK(k) {                                                         \
    float2 s0, s1, s2;                                                     \
    asm("v_pk_mul_f32 %0, %3, %3\n\t"                                      \
        "v_pk_mul_f32 %1, %4, %4\n\t"                                      \
        "v_pk_mul_f32 %2, %5, %5\n\t"                                      \
        "v_pk_add_f32 %0, %0, %1\n\t"                                      \
        "v_pk_add_f32 %0, %0, %2"                                          \
        : "=&v"(s0), "=&v"(s1), "=&v"(s2)                                  \
        : "v"(x_##k), "v"(y_##k), "v"(z_##k));                             \
    p_##k = s0; }
  REP8(PSUMK)
#undef PSUMK
  if (t < NANCH) s_cnt[t] = 0;
  __syncthreads();

  const float R2 = (float)(0.4 * 0.4);
  const float2 mm2 = make_float2(-2.0f, -2.0f);
  for (int a = 0; a < NANCH; ++a) {
    const float4 A = s_anch[a];
    const float ax = A.x, ay = A.y, az = A.z;
    const float asum = __fadd_rn(__fadd_rn(__fmul_rn(ax, ax), __fmul_rn(ay, ay)),
                                 __fmul_rn(az, az));
    const float2 ax2 = make_float2(ax, ax);
    const float2 ay2 = make_float2(ay, ay);
    const float2 az2 = make_float2(az, az);
    const float2 as2 = make_float2(asum, asum);
    int cw = 0;
    // per elem: d = (((-2*(((ax*X)+(ay*Y))+(az*Z))) + asum) + psum), rn each
#define CNTK(k) {                                                          \
    float2 d0, d1, d2v;                                                    \
    asm("v_pk_mul_f32 %0, %3, %6\n\t"                                      \
        "v_pk_mul_f32 %1, %4, %7\n\t"                                      \
        "v_pk_mul_f32 %2, %5, %8\n\t"                                      \
        "v_pk_add_f32 %0, %0, %1\n\t"                                      \
        "v_pk_add_f32 %0, %0, %2\n\t"                                      \
        "v_pk_mul_f32 %0, %0, %9\n\t"                                      \
        "v_pk_add_f32 %0, %0, %10\n\t"                                     \
        "v_pk_add_f32 %0, %0, %11"                                         \
        : "=&v"(d0), "=&v"(d1), "=&v"(d2v)                                 \
        : "v"(x_##k), "v"(y_##k), "v"(z_##k), "v"(ax2), "v"(ay2), "v"(az2),\
          "v"(mm2), "v"(as2), "v"(p_##k));                                 \
    cw += (int)__popcll(__ballot(d0.x < R2));                              \
    cw += (int)__popcll(__ballot(d0.y < R2)); }
    REP8(CNTK)
#undef CNTK
    if (lane == 0) atomicAdd(&s_cnt[a], cw);
  }
  __syncthreads();

  if (t == 0) {
    unsigned long long used = 0ULL;
    for (int r = 0; r < TOPK; ++r) {
      int bestc = -1, besta = 0;
      for (int a = 0; a < NANCH; ++a) {
        if (used & (1ULL << a)) continue;
        int c = s_cnt[a];
        c = c < BALLK ? c : BALLK;
        if (c > bestc) { bestc = c; besta = a; }   // strict > : lowest slot on ties
      }
      used |= 1ULL << besta;
      s_t4[r] = besta;
    }
  }
  __syncthreads();

  // ---- two 128-NN searches: anchors j = 2p, 2p+1 ----
  for (int jj = 0; jj < 2; ++jj) {
    const int j = 2 * p + jj;
    const float4 A = s_anch[s_t4[j]];
    const float ax = A.x, ay = A.y, az = A.z;
    const float asum = __fadd_rn(__fadd_rn(__fmul_rn(ax, ax), __fmul_rn(ay, ay)),
                                 __fmul_rn(az, az));
    const float2 ax2 = make_float2(ax, ax);
    const float2 ay2 = make_float2(ay, ay);
    const float2 az2 = make_float2(az, az);
    const float2 as2 = make_float2(asum, asum);
#define DECLKK(k) unsigned long long ka_##k, kb_##k;
    REP8(DECLKK)
#undef DECLKK
#define KEYK(k) {                                                          \
    float2 d0, d1, d2v;                                                    \
    asm("v_pk_mul_f32 %0, %3, %6\n\t"                                      \
        "v_pk_mul_f32 %1, %4, %7\n\t"                                      \
        "v_pk_mul_f32 %2, %5, %8\n\t"                                      \
        "v_pk_add_f32 %0, %0, %1\n\t"                                      \
        "v_pk_add_f32 %0, %0, %2\n\t"                                      \
        "v_pk_mul_f32 %0, %0, %9\n\t"                                      \
        "v_pk_add_f32 %0, %0, %10\n\t"                                     \
        "v_pk_add_f32 %0, %0, %11"                                         \
        : "=&v"(d0), "=&v"(d1), "=&v"(d2v)                                 \
        : "v"(x_##k), "v"(y_##k), "v"(z_##k), "v"(ax2), "v"(ay2), "v"(az2),\
          "v"(mm2), "v"(as2), "v"(p_##k));                                 \
    const int i2 = ((k) << 11) + (t << 1);                                 \
    ka_##k = ((unsigned long long)f2key(d0.x) << 32) | (uint32_t)i2;       \
    kb_##k = ((unsigned long long)f2key(d0.y) << 32) | (uint32_t)(i2 + 1); }
    REP8(KEYK)
#undef KEYK
    for (int r = 0; r < NBH; ++r) {
#define PMINK(k) const unsigned long long w_##k = ka_##k < kb_##k ? ka_##k : kb_##k;
      REP8(PMINK)
#undef PMINK
      const unsigned long long q0 = w_0 < w_4 ? w_0 : w_4;
      const unsigned long long q1 = w_1 < w_5 ? w_1 : w_5;
      const unsigned long long q2 = w_2 < w_6 ? w_2 : w_6;
      const unsigned long long q3 = w_3 < w_7 ? w_3 : w_7;
      const unsigned long long r0m = q0 < q2 ? q0 : q2;
      const unsigned long long r1m = q1 < q3 ? q1 : q3;
      unsigned long long m = r0m < r1m ? r0m : r1m;

      DPP_MIN64(m, CTRL_XOR1);
      DPP_MIN64(m, CTRL_XOR2);
      DPP_MIN64(m, CTRL_ROR4);
      DPP_MIN64(m, CTRL_ROR8);
      SWZ16_MIN64(m);
      SHF32_MIN64(m);

      const int par = r & 1;
      if (lane == 0) s_key[par][wS] = m;
      __syncthreads();
      unsigned long long g = s_key[par][lane & 15];
      DPP_MIN64(g, CTRL_XOR1);
      DPP_MIN64(g, CTRL_XOR2);
      DPP_MIN64(g, CTRL_ROR4);
      DPP_MIN64(g, CTRL_ROR8);
      if (t == 0) s_knn[r] = (int)(uint32_t)g;
#define KILLK(k) { if (ka_##k == g) ka_##k = ~0ULL; if (kb_##k == g) kb_##k = ~0ULL; }
      REP8(KILLK)
#undef KILLK
    }
    __syncthreads();
    // write roi1 & roi2 rows for anchor j
    if (t < NBH) {
      const int idx = s_knn[t];
      const float X = px[idx], Y = py[idx], Z = pz[idx];
      float* o1 = out + ((size_t)b * 1536 + (j << 7) + t) * 3;
      float* o2 = o1 + 512 * 3;
      o1[0] = X; o1[1] = Y; o1[2] = Z;
      o2[0] = X; o2[1] = Y; o2[2] = Z;
    }
    __syncthreads();
  }
}

extern "C" void kernel_launch(void* const* d_in, const int* in_sizes, int n_in,
                              void* d_out, int out_size, void* d_ws, size_t ws_size,
                              hipStream_t stream) {
  const float* pts = (const float*)d_in[0];   // [16, 3, 16384]
  float* out = (float*)d_out;                 // [16, 1536, 3]
  (void)d_ws; (void)ws_size;
  mega_kernel<<<dim3(BATCH + 2 * BATCH), dim3(FT), 0, stream>>>(pts, out);
}